// Round 2
// baseline (132.092 us; speedup 1.0000x reference)
//
#include <hip/hip_runtime.h>
#include <math.h>
#include <stdint.h>

// Problem constants (static per reference)
#define BB 8
#define NN 384
#define FF 64
#define TT 192
#define NSRC 383          // T + TAU - 1
#define NSINK 192
#define SS 5
#define NEDGE 441600      // B * 55200
#define BN (BB * NN)      // 3072
#define TILE_E 256        // edges per block (4 waves x 64 edges... now 4 passes x 16)
#define NBLKE (NEDGE / TILE_E)    // 1725 exactly
#define OUTV ((BB * NN * NN) / 4) // 294912 float4 to zero

typedef _Float16 half8 __attribute__((ext_vector_type(8)));
typedef __fp16 fp16x2 __attribute__((ext_vector_type(2)));
typedef float floatx4 __attribute__((ext_vector_type(4)));
typedef uint32_t uint4v __attribute__((ext_vector_type(4)));

// 2-limb f16 split (prep side, RNE): x ~= h + l/512
static __device__ __forceinline__ void split_f16(float x, uint16_t& h, uint16_t& l) {
  const _Float16 hh = (_Float16)x;
  const float hb = (float)hh;
  const _Float16 ll = (_Float16)((x - hb) * 512.f);
  h = __builtin_bit_cast(uint16_t, hh);
  l = __builtin_bit_cast(uint16_t, ll);
}

// pair split via v_cvt_pkrtz (RTZ hi; residual captured exactly by the lo limb)
static __device__ __forceinline__ void split_pair(float x0, float x1,
                                                  uint32_t& hi, uint32_t& lo) {
  const fp16x2 h = __builtin_amdgcn_cvt_pkrtz(x0, x1);
  const float hb0 = (float)h.x, hb1 = (float)h.y;
  const fp16x2 l = __builtin_amdgcn_cvt_pkrtz((x0 - hb0) * 512.f, (x1 - hb1) * 512.f);
  hi = __builtin_bit_cast(uint32_t, h);
  lo = __builtin_bit_cast(uint32_t, l);
}

// ---------------- prep: node projections + weight folding + W f16-limb frags ----------------
// A stays row-major [bn][f].
// Bv is stored f-major-blocked: float4 element index = (f>>2)*BN + bn, component f&3.
// W frag slab (A-operand layout, per limb): ushort idx = (((jt*2+kc)*4+q)*16 + m)*8 + jj
//   <-> W[k = 32*kc + 8*q + jj][j = 16*jt + m]   (g1-folded weight)
__global__ __launch_bounds__(64) void prep_all(
    const float* __restrict__ nodes, const float* __restrict__ w1,
    const float* __restrict__ b1,
    const float* __restrict__ w2, const float* __restrict__ b2,
    const float* __restrict__ g1, const float* __restrict__ be1,
    const float* __restrict__ g2, const float* __restrict__ be2,
    const float* __restrict__ w3, const float* __restrict__ b3,
    float* __restrict__ A, float* __restrict__ Bv,
    unsigned short* __restrict__ Whg, unsigned short* __restrict__ Wlg,
    float* __restrict__ wcol, float* __restrict__ cb,
    float* __restrict__ gw, float* __restrict__ cwsgw) {
  const int blk = blockIdx.x;
  const int k = threadIdx.x;
  if (blk < BN / 4) {
    const int bn0 = blk * 4;
    __shared__ float nd[4][FF];
#pragma unroll
    for (int i = 0; i < 4; ++i) nd[i][k] = nodes[(bn0 + i) * FF + k];
    __syncthreads();
    const float bk = b1[k];
    float a0 = bk, a1 = bk, a2 = bk, a3 = bk;
    float q0 = 0.f, q1 = 0.f, q2 = 0.f, q3 = 0.f;
#pragma unroll 8
    for (int f = 0; f < FF; ++f) {
      const float wt = w1[f * FF + k];
      const float wb = w1[(FF + f) * FF + k];
      const float n0 = nd[0][f], n1 = nd[1][f], n2 = nd[2][f], n3 = nd[3][f];
      a0 = fmaf(n0, wt, a0); a1 = fmaf(n1, wt, a1);
      a2 = fmaf(n2, wt, a2); a3 = fmaf(n3, wt, a3);
      q0 = fmaf(n0, wb, q0); q1 = fmaf(n1, wb, q1);
      q2 = fmaf(n2, wb, q2); q3 = fmaf(n3, wb, q3);
    }
    A[(bn0 + 0) * FF + k] = a0;
    A[(bn0 + 1) * FF + k] = a1;
    A[(bn0 + 2) * FF + k] = a2;
    A[(bn0 + 3) * FF + k] = a3;
    // transposed (f-major-blocked) Bv writes
    const int f4 = k >> 2, ff = k & 3;
    Bv[(f4 * BN + (bn0 + 0)) * 4 + ff] = q0;
    Bv[(f4 * BN + (bn0 + 1)) * 4 + ff] = q1;
    Bv[(f4 * BN + (bn0 + 2)) * 4 + ff] = q2;
    Bv[(f4 * BN + (bn0 + 3)) * 4 + ff] = q3;
  } else {
    const int j = k;
    const int jt = j >> 4, m = j & 15;
    float cbj = b2[j];
    float wc = 0.f;
    for (int kk = 0; kk < FF; ++kk) {
      const float wraw = w2[kk * FF + j];
      const float w = g1[kk] * wraw;
      wc += w;
      cbj = fmaf(be1[kk], wraw, cbj);
      uint16_t hu, lu;
      split_f16(w, hu, lu);
      const int kc = kk >> 5, qq = (kk >> 3) & 3, jj = kk & 7;
      const int idx = (((jt * 2 + kc) * 4 + qq) * 16 + m) * 8 + jj;
      Whg[idx] = hu;
      Wlg[idx] = lu;
    }
    wcol[j] = wc;
    cb[j] = cbj;
    const float gwj = g2[j] * w3[j];
    gw[j] = gwj;
    __shared__ float sA[FF], sB[FF];
    sA[j] = gwj;
    sB[j] = be2[j] * w3[j];
    __syncthreads();
    if (j == 0) {
      float a = 0.f, bq = 0.f;
      for (int i = 0; i < FF; ++i) { a += sA[i]; bq += sB[i]; }
      cwsgw[0] = b3[0] + bq;
      cwsgw[1] = a;
    }
  }
}

// ---------------- main: MFMA edge MLP, transpose-free ----------------
// 256 thr = 4 waves. Wave owns 64 consecutive edges, processed as 4 passes of 16.
// Lane role (q = lane>>4, n = lane&15) IS the MFMA B-frag layout: per pass et,
// lane (q,n) gathers the k-slice {8q..8q+8} U {32+8q..32+8q+8} of edge 16*et+n
// directly -> no LDS transpose at all. LDS holds only the 16 KB W frag table.
// LN stats: per-lane 16-elem partials + shfl_xor(16,32) tree (bit-identical
// across the 4 q-lanes of an edge).
__global__ __launch_bounds__(256, 3) void edge_mlp(
    const float* __restrict__ A, const float* __restrict__ Bv,
    const unsigned short* __restrict__ Whg, const unsigned short* __restrict__ Wlg,
    const float* __restrict__ wcolg, const float* __restrict__ cbg,
    const float* __restrict__ gwg, const float* __restrict__ cwsgw,
    const int* __restrict__ bidx, const int* __restrict__ ridx,
    const int* __restrict__ cidx, float* __restrict__ L,
    float4* __restrict__ outv) {
  __shared__ __align__(16) unsigned short WhS[4096];   // 8 KB W hi frags
  __shared__ __align__(16) unsigned short WlS[4096];   // 8 KB W lo frags

  const int tid = threadIdx.x;       // 0..255
  const int lane = tid & 63;
  const int q = lane >> 4;           // k-quad
  const int n = lane & 15;           // edge column within pass

  // ---- stage W frag table into LDS (one-time, 16 KB) ----
  {
    const int4* gh = (const int4*)Whg;
    const int4* gl = (const int4*)Wlg;
    int4* sh = (int4*)WhS;
    int4* sl = (int4*)WlS;
    sh[tid] = gh[tid];
    sh[tid + 256] = gh[tid + 256];
    sl[tid] = gl[tid];
    sl[tid + 256] = gl[tid + 256];
  }

  // fused zeroing of the output grid
  const int gtid = blockIdx.x * 256 + tid;
  if (gtid < OUTV) outv[gtid] = make_float4(0.f, 0.f, 0.f, 0.f);

  // ---- preload edge indices for all 4 passes (lane-local: edge 64*wave+16*et+n) ----
  const int ebase = blockIdx.x * TILE_E + (tid >> 6) * 64 + n;
  int eb[4], er[4], ec[4];
#pragma unroll
  for (int et = 0; et < 4; ++et) {
    eb[et] = bidx[ebase + 16 * et];
    er[et] = ridx[ebase + 16 * et];
    ec[et] = cidx[ebase + 16 * et];
  }
  const float cw = cwsgw[0], sgw = cwsgw[1];
  const float4* __restrict__ pb4 = (const float4*)Bv;   // [16][BN] float4

  __syncthreads();   // W table visible; only barrier in the kernel

  // ---- 4 passes: gather -> relu/split -> stats -> MFMA -> LN epilogue -> store ----
#pragma unroll
  for (int et = 0; et < 4; ++et) {
    const int b = eb[et], r = er[et], c = ec[et];
    const float4* pa = (const float4*)(A + (b * NN + r) * FF);
    const int colB = b * NN + c;
    // k-slices: kc=0 -> k in [8q, 8q+8);  kc=1 -> k in [32+8q, 32+8q+8)
    const float4 a0 = pa[2 * q],     a1 = pa[2 * q + 1];
    const float4 a2 = pa[8 + 2 * q], a3 = pa[8 + 2 * q + 1];
    const float4 v0 = pb4[(2 * q) * BN + colB];
    const float4 v1 = pb4[(2 * q + 1) * BN + colB];
    const float4 v2 = pb4[(8 + 2 * q) * BN + colB];
    const float4 v3 = pb4[(8 + 2 * q + 1) * BN + colB];

    const float x0 = fmaxf(a0.x + v0.x, 0.f);
    const float x1 = fmaxf(a0.y + v0.y, 0.f);
    const float x2 = fmaxf(a0.z + v0.z, 0.f);
    const float x3 = fmaxf(a0.w + v0.w, 0.f);
    const float x4 = fmaxf(a1.x + v1.x, 0.f);
    const float x5 = fmaxf(a1.y + v1.y, 0.f);
    const float x6 = fmaxf(a1.z + v1.z, 0.f);
    const float x7 = fmaxf(a1.w + v1.w, 0.f);
    const float x8 = fmaxf(a2.x + v2.x, 0.f);
    const float x9 = fmaxf(a2.y + v2.y, 0.f);
    const float x10 = fmaxf(a2.z + v2.z, 0.f);
    const float x11 = fmaxf(a2.w + v2.w, 0.f);
    const float x12 = fmaxf(a3.x + v3.x, 0.f);
    const float x13 = fmaxf(a3.y + v3.y, 0.f);
    const float x14 = fmaxf(a3.z + v3.z, 0.f);
    const float x15 = fmaxf(a3.w + v3.w, 0.f);

    // split into MFMA B-operand limbs (jj order = consecutive k)
    uint32_t h0, l0, h1, l1, h2, l2, h3, l3;
    split_pair(x0, x1, h0, l0); split_pair(x2, x3, h1, l1);
    split_pair(x4, x5, h2, l2); split_pair(x6, x7, h3, l3);
    const uint4v hv0 = {h0, h1, h2, h3}, lv0 = {l0, l1, l2, l3};
    const half8 xh0 = __builtin_bit_cast(half8, hv0);
    const half8 xl0 = __builtin_bit_cast(half8, lv0);
    split_pair(x8, x9, h0, l0);  split_pair(x10, x11, h1, l1);
    split_pair(x12, x13, h2, l2); split_pair(x14, x15, h3, l3);
    const uint4v hv1 = {h0, h1, h2, h3}, lv1 = {l0, l1, l2, l3};
    const half8 xh1 = __builtin_bit_cast(half8, hv1);
    const half8 xl1 = __builtin_bit_cast(half8, lv1);

    // LN1 stats: per-lane 16-elem partials, then cross-q tree (commutative adds
    // -> bit-identical in all 4 q-lanes of the edge)
    float s = x0 + x1 + x2 + x3 + x4 + x5 + x6 + x7 +
              x8 + x9 + x10 + x11 + x12 + x13 + x14 + x15;
    float qa = 0.f;
    qa = fmaf(x0, x0, qa); qa = fmaf(x1, x1, qa);
    qa = fmaf(x2, x2, qa); qa = fmaf(x3, x3, qa);
    qa = fmaf(x4, x4, qa); qa = fmaf(x5, x5, qa);
    qa = fmaf(x6, x6, qa); qa = fmaf(x7, x7, qa);
    qa = fmaf(x8, x8, qa); qa = fmaf(x9, x9, qa);
    qa = fmaf(x10, x10, qa); qa = fmaf(x11, x11, qa);
    qa = fmaf(x12, x12, qa); qa = fmaf(x13, x13, qa);
    qa = fmaf(x14, x14, qa); qa = fmaf(x15, x15, qa);
    s += __shfl_xor(s, 16, 64);  s += __shfl_xor(s, 32, 64);
    qa += __shfl_xor(qa, 16, 64); qa += __shfl_xor(qa, 32, 64);
    const float mu = s * (1.f / FF);
    const float rstd = 1.f / sqrtf(qa * (1.f / FF) - mu * mu + 1e-5f);

    // ---- MFMA: W frags streamed from LDS (conflict-free b128 reads) ----
    floatx4 acc0[4], acc1[4];
#pragma unroll
    for (int jt = 0; jt < 4; ++jt) {
      acc0[jt] = (floatx4){0.f, 0.f, 0.f, 0.f};
      acc1[jt] = (floatx4){0.f, 0.f, 0.f, 0.f};
    }
#pragma unroll
    for (int kc = 0; kc < 2; ++kc) {
      const half8 xh = kc ? xh1 : xh0;
      const half8 xl = kc ? xl1 : xl0;
#pragma unroll
      for (int jt = 0; jt < 4; ++jt) {
        const int woff = (((jt * 2 + kc) * 4 + q) * 16 + n) * 8;
        const half8 wh = *(const half8*)&WhS[woff];
        const half8 wl = *(const half8*)&WlS[woff];
        acc0[jt] = __builtin_amdgcn_mfma_f32_16x16x32_f16(wh, xh, acc0[jt], 0, 0, 0);
        acc1[jt] = __builtin_amdgcn_mfma_f32_16x16x32_f16(wh, xl, acc1[jt], 0, 0, 0);
        acc1[jt] = __builtin_amdgcn_mfma_f32_16x16x32_f16(wl, xh, acc1[jt], 0, 0, 0);
      }
    }

    // ---- epilogue: LN1-apply + relu + LN2-reduce (D col = n -> all lane-local) ----
    float s1 = 0.f, sq2 = 0.f, s3 = 0.f;
#pragma unroll
    for (int jt = 0; jt < 4; ++jt) {
      const floatx4 wc4 = *(const floatx4*)(wcolg + 16 * jt + 4 * q);
      const floatx4 cb4 = *(const floatx4*)(cbg + 16 * jt + 4 * q);
      const floatx4 gw4 = *(const floatx4*)(gwg + 16 * jt + 4 * q);
      const floatx4 t4 = acc0[jt] + acc1[jt] * (1.f / 512.f);
#pragma unroll
      for (int rg = 0; rg < 4; ++rg) {
        const float pre = fmaf(rstd, fmaf(-mu, wc4[rg], t4[rg]), cb4[rg]);
        const float tr = fmaxf(pre, 0.f);
        s1 += tr;
        sq2 = fmaf(tr, tr, sq2);
        s3 = fmaf(tr, gw4[rg], s3);
      }
    }
    // sum over the 4 quads (disjoint 16-j subsets)
    s1 += __shfl_xor(s1, 16, 64);  s1 += __shfl_xor(s1, 32, 64);
    sq2 += __shfl_xor(sq2, 16, 64); sq2 += __shfl_xor(sq2, 32, 64);
    s3 += __shfl_xor(s3, 16, 64);  s3 += __shfl_xor(s3, 32, 64);
    if (q == 0) {
      const float mu2 = s1 * (1.f / FF);
      const float var2 = sq2 * (1.f / FF) - mu2 * mu2;
      const float rstd2 = 1.f / sqrtf(var2 + 1e-5f);
      const float logit = fmaf(rstd2, fmaf(-mu2, sgw, s3), cw);
      L[(b * NSINK + (r - TT)) * NSRC + c] = logit;
    }
  }
}

// ---------------- argmax over sources + scatter ones ----------------
// One wave per (b, row) pair; all S=5 samples fused (L row read once).
__global__ __launch_bounds__(256) void argmax_scatter(
    const float* __restrict__ L, const float* __restrict__ gum,
    float* __restrict__ out) {
  const int pair = blockIdx.x * 4 + (threadIdx.x >> 6);  // b*192 + row
  const int lane = threadIdx.x & 63;
  const int row = pair % NSINK;
  const int b = pair / NSINK;
  const int r = row + TT;

  const float* __restrict__ lrow = L + (b * NSINK + row) * NSRC;
  const float* __restrict__ g0 = gum + (b * NSINK + row) * NSRC;
  const int sstr = BB * NSINK * NSRC;   // sample stride in floats

  float bv0 = -INFINITY, bv1 = -INFINITY, bv2 = -INFINITY, bv3 = -INFINITY, bv4 = -INFINITY;
  int bi0 = 0, bi1 = 0, bi2 = 0, bi3 = 0, bi4 = 0;
  for (int cc = lane; cc < r; cc += 64) {
    const float lv = lrow[cc];
    const float v0 = lv + g0[0 * sstr + cc];
    const float v1 = lv + g0[1 * sstr + cc];
    const float v2 = lv + g0[2 * sstr + cc];
    const float v3 = lv + g0[3 * sstr + cc];
    const float v4 = lv + g0[4 * sstr + cc];
    if (v0 > bv0) { bv0 = v0; bi0 = cc; }   // strict > keeps smallest index per lane
    if (v1 > bv1) { bv1 = v1; bi1 = cc; }
    if (v2 > bv2) { bv2 = v2; bi2 = cc; }
    if (v3 > bv3) { bv3 = v3; bi3 = cc; }
    if (v4 > bv4) { bv4 = v4; bi4 = cc; }
  }
#pragma unroll
  for (int off = 32; off > 0; off >>= 1) {
    {
      const float ov = __shfl_xor(bv0, off, 64); const int oi = __shfl_xor(bi0, off, 64);
      if (ov > bv0 || (ov == bv0 && oi < bi0)) { bv0 = ov; bi0 = oi; }
    }
    {
      const float ov = __shfl_xor(bv1, off, 64); const int oi = __shfl_xor(bi1, off, 64);
      if (ov > bv1 || (ov == bv1 && oi < bi1)) { bv1 = ov; bi1 = oi; }
    }
    {
      const float ov = __shfl_xor(bv2, off, 64); const int oi = __shfl_xor(bi2, off, 64);
      if (ov > bv2 || (ov == bv2 && oi < bi2)) { bv2 = ov; bi2 = oi; }
    }
    {
      const float ov = __shfl_xor(bv3, off, 64); const int oi = __shfl_xor(bi3, off, 64);
      if (ov > bv3 || (ov == bv3 && oi < bi3)) { bv3 = ov; bi3 = oi; }
    }
    {
      const float ov = __shfl_xor(bv4, off, 64); const int oi = __shfl_xor(bi4, off, 64);
      if (ov > bv4 || (ov == bv4 && oi < bi4)) { bv4 = ov; bi4 = oi; }
    }
  }
  if (lane == 0) {
    float* __restrict__ orow = out + (b * NN + r) * NN;
    orow[bi0] = 1.0f;
    orow[bi1] = 1.0f;
    orow[bi2] = 1.0f;
    orow[bi3] = 1.0f;
    orow[bi4] = 1.0f;
  }
}

extern "C" void kernel_launch(void* const* d_in, const int* in_sizes, int n_in,
                              void* d_out, int out_size, void* d_ws, size_t ws_size,
                              hipStream_t stream) {
  const float* nodes = (const float*)d_in[0];
  const float* w1 = (const float*)d_in[1];
  const float* b1 = (const float*)d_in[2];
  const float* g1 = (const float*)d_in[3];
  const float* be1 = (const float*)d_in[4];
  const float* w2 = (const float*)d_in[5];
  const float* b2 = (const float*)d_in[6];
  const float* g2 = (const float*)d_in[7];
  const float* be2 = (const float*)d_in[8];
  const float* w3 = (const float*)d_in[9];
  const float* b3 = (const float*)d_in[10];
  const float* gum = (const float*)d_in[11];
  const int* bidx = (const int*)d_in[12];
  const int* ridx = (const int*)d_in[13];
  const int* cidx = (const int*)d_in[14];
  float* out = (float*)d_out;

  // workspace layout (floats)
  float* ws = (float*)d_ws;
  float* A = ws;                       // 8*384*64 = 196608
  float* Bv = A + BN * FF;             // 196608 (f-major-blocked float4 layout)
  unsigned short* Whg = (unsigned short*)(ws + 393216);  // 4096 ushort (8 KB)
  unsigned short* Wlg = Whg + 4096;                      // 4096 ushort -> ends at float 397312
  float* wcol = ws + 397312;           // 64
  float* cb = wcol + FF;               // 64
  float* gw = cb + FF;                 // 64
  float* cwsgw = gw + FF;              // 2
  float* L = ws + 397520;              // 8*192*383 = 588288
  (void)ws_size; (void)n_in; (void)in_sizes; (void)out_size;

  hipLaunchKernelGGL(prep_all, dim3(BN / 4 + 1), dim3(64), 0, stream,
                     nodes, w1, b1, w2, b2, g1, be1, g2, be2, w3, b3,
                     A, Bv, Whg, Wlg, wcol, cb, gw, cwsgw);
  hipLaunchKernelGGL(edge_mlp, dim3(NBLKE), dim3(256), 0, stream,
                     A, Bv, Whg, Wlg, wcol, cb, gw, cwsgw, bidx, ridx, cidx, L,
                     (float4*)out);
  hipLaunchKernelGGL(argmax_scatter, dim3((BB * NSINK) / 4), dim3(256), 0, stream,
                     L, gum, out);
}

// Round 3
// 129.061 us; speedup vs baseline: 1.0235x; 1.0235x over previous
//
#include <hip/hip_runtime.h>
#include <math.h>
#include <stdint.h>

// Problem constants (static per reference)
#define BB 8
#define NN 384
#define FF 64
#define TT 192
#define NSRC 383          // T + TAU - 1
#define NSINK 192
#define SS 5
#define NEDGE 441600      // B * 55200
#define BN (BB * NN)      // 3072
#define OUTV ((BB * NN * NN) / 4) // 294912 float4 to zero
#define TPB_TASK 957      // wave-tiles per batch: 3 + 4*64 + 5*64 + 6*63
#define NTASK (BB * TPB_TASK)     // 7656
#define NBLK_T (NTASK / 4)        // 1914 blocks of 4 waves

typedef _Float16 half8 __attribute__((ext_vector_type(8)));
typedef __fp16 fp16x2 __attribute__((ext_vector_type(2)));
typedef float floatx4 __attribute__((ext_vector_type(4)));
typedef uint32_t uint4v __attribute__((ext_vector_type(4)));

// 2-limb f16 split (prep side, RNE): x ~= h + l/512
static __device__ __forceinline__ void split_f16(float x, uint16_t& h, uint16_t& l) {
  const _Float16 hh = (_Float16)x;
  const float hb = (float)hh;
  const _Float16 ll = (_Float16)((x - hb) * 512.f);
  h = __builtin_bit_cast(uint16_t, hh);
  l = __builtin_bit_cast(uint16_t, ll);
}

// pair split via v_cvt_pkrtz (RTZ hi; residual captured exactly by the lo limb)
static __device__ __forceinline__ void split_pair(float x0, float x1,
                                                  uint32_t& hi, uint32_t& lo) {
  const fp16x2 h = __builtin_amdgcn_cvt_pkrtz(x0, x1);
  const float hb0 = (float)h.x, hb1 = (float)h.y;
  const fp16x2 l = __builtin_amdgcn_cvt_pkrtz((x0 - hb0) * 512.f, (x1 - hb1) * 512.f);
  hi = __builtin_bit_cast(uint32_t, h);
  lo = __builtin_bit_cast(uint32_t, l);
}

// ---------------- prep: node projections + weight folding + W frags + task table ----------------
// A stays row-major [bn][f].
// Bv is stored f-major-blocked: float4 element index = (f>>2)*BN + bn, component f&3.
// W frag slab (A-operand layout, per limb): ushort idx = (((jt*2+kc)*4+q)*16 + m)*8 + jj
//   <-> W[k = 32*kc + 8*q + jj][j = 16*jt + m]   (g1-folded weight)
// Task table: one entry per wave-tile {(r<<16)|c0, b}; row r has ceil(r/64) tiles.
__global__ __launch_bounds__(64) void prep_all(
    const float* __restrict__ nodes, const float* __restrict__ w1,
    const float* __restrict__ b1,
    const float* __restrict__ w2, const float* __restrict__ b2,
    const float* __restrict__ g1, const float* __restrict__ be1,
    const float* __restrict__ g2, const float* __restrict__ be2,
    const float* __restrict__ w3, const float* __restrict__ b3,
    float* __restrict__ A, float* __restrict__ Bv,
    unsigned short* __restrict__ Whg, unsigned short* __restrict__ Wlg,
    float* __restrict__ wcol, float* __restrict__ cb,
    float* __restrict__ gw, float* __restrict__ cwsgw,
    int2* __restrict__ tab) {
  const int blk = blockIdx.x;
  const int k = threadIdx.x;
  if (blk < BN / 4) {
    const int bn0 = blk * 4;
    __shared__ float nd[4][FF];
#pragma unroll
    for (int i = 0; i < 4; ++i) nd[i][k] = nodes[(bn0 + i) * FF + k];
    __syncthreads();
    const float bk = b1[k];
    float a0 = bk, a1 = bk, a2 = bk, a3 = bk;
    float q0 = 0.f, q1 = 0.f, q2 = 0.f, q3 = 0.f;
#pragma unroll 8
    for (int f = 0; f < FF; ++f) {
      const float wt = w1[f * FF + k];
      const float wb = w1[(FF + f) * FF + k];
      const float n0 = nd[0][f], n1 = nd[1][f], n2 = nd[2][f], n3 = nd[3][f];
      a0 = fmaf(n0, wt, a0); a1 = fmaf(n1, wt, a1);
      a2 = fmaf(n2, wt, a2); a3 = fmaf(n3, wt, a3);
      q0 = fmaf(n0, wb, q0); q1 = fmaf(n1, wb, q1);
      q2 = fmaf(n2, wb, q2); q3 = fmaf(n3, wb, q3);
    }
    A[(bn0 + 0) * FF + k] = a0;
    A[(bn0 + 1) * FF + k] = a1;
    A[(bn0 + 2) * FF + k] = a2;
    A[(bn0 + 3) * FF + k] = a3;
    // transposed (f-major-blocked) Bv writes
    const int f4 = k >> 2, ff = k & 3;
    Bv[(f4 * BN + (bn0 + 0)) * 4 + ff] = q0;
    Bv[(f4 * BN + (bn0 + 1)) * 4 + ff] = q1;
    Bv[(f4 * BN + (bn0 + 2)) * 4 + ff] = q2;
    Bv[(f4 * BN + (bn0 + 3)) * 4 + ff] = q3;
  } else if (blk == BN / 4) {
    const int j = k;
    const int jt = j >> 4, m = j & 15;
    float cbj = b2[j];
    float wc = 0.f;
    for (int kk = 0; kk < FF; ++kk) {
      const float wraw = w2[kk * FF + j];
      const float w = g1[kk] * wraw;
      wc += w;
      cbj = fmaf(be1[kk], wraw, cbj);
      uint16_t hu, lu;
      split_f16(w, hu, lu);
      const int kc = kk >> 5, qq = (kk >> 3) & 3, jj = kk & 7;
      const int idx = (((jt * 2 + kc) * 4 + qq) * 16 + m) * 8 + jj;
      Whg[idx] = hu;
      Wlg[idx] = lu;
    }
    wcol[j] = wc;
    cb[j] = cbj;
    const float gwj = g2[j] * w3[j];
    gw[j] = gwj;
    __shared__ float sA[FF], sB[FF];
    sA[j] = gwj;
    sB[j] = be2[j] * w3[j];
    __syncthreads();
    if (j == 0) {
      float a = 0.f, bq = 0.f;
      for (int i = 0; i < FF; ++i) { a += sA[i]; bq += sB[i]; }
      cwsgw[0] = b3[0] + bq;
      cwsgw[1] = a;
    }
  } else {
    // ---- wave-task table: cumulative-tile closed form ----
    for (int rr = k; rr < NSINK; rr += 64) {
      const int r = TT + rr;
      int tb;
      if (r == 192) tb = 0;
      else if (r < 257) tb = 3 + 4 * (r - 193);
      else if (r < 321) tb = 259 + 5 * (r - 257);
      else tb = 579 + 6 * (r - 321);
      const int nt = (r + 63) >> 6;
      for (int b = 0; b < BB; ++b)
        for (int i = 0; i < nt; ++i)
          tab[b * TPB_TASK + tb + i] = make_int2((r << 16) | (i * 64), b);
    }
  }
}

// ---------------- main: MFMA edge MLP, row-tiled, transpose-free ----------------
// 256 thr = 4 waves; wave owns one task (b, r, c0): 64 consecutive source cols of
// one sink row, processed as 4 passes of 16 edges. Lane role (q=lane>>4, n=lane&15)
// IS the MFMA B-frag layout. A-row loaded once per wave; Bv contiguous per q-group;
// next-pass Bv prefetched during compute. Ragged tail masked at store (c < r).
// LDS: 16 KB W frag table + 768 B epilogue constants.
__global__ __launch_bounds__(256, 3) void edge_mlp(
    const float* __restrict__ A, const float* __restrict__ Bv,
    const unsigned short* __restrict__ Whg, const unsigned short* __restrict__ Wlg,
    const float* __restrict__ wcolg, const float* __restrict__ cbg,
    const float* __restrict__ gwg, const float* __restrict__ cwsgw,
    const int2* __restrict__ tab, float* __restrict__ L,
    float4* __restrict__ outv) {
  __shared__ __align__(16) unsigned short WhS[4096];   // 8 KB W hi frags
  __shared__ __align__(16) unsigned short WlS[4096];   // 8 KB W lo frags
  __shared__ __align__(16) float wcolS[FF], cbS[FF], gwS[FF];

  const int tid = threadIdx.x;       // 0..255
  const int wave = tid >> 6;
  const int lane = tid & 63;
  const int q = lane >> 4;           // k-quad
  const int n = lane & 15;           // edge column within pass

  // ---- stage W frag table + epilogue constants into LDS ----
  {
    const int4* gh = (const int4*)Whg;
    const int4* gl = (const int4*)Wlg;
    int4* sh = (int4*)WhS;
    int4* sl = (int4*)WlS;
    sh[tid] = gh[tid];
    sh[tid + 256] = gh[tid + 256];
    sl[tid] = gl[tid];
    sl[tid + 256] = gl[tid + 256];
    if (tid < FF) {
      wcolS[tid] = wcolg[tid];
      cbS[tid] = cbg[tid];
      gwS[tid] = gwg[tid];
    }
  }

  // fused zeroing of the output grid
  const int gtid = blockIdx.x * 256 + tid;
  if (gtid < OUTV) outv[gtid] = make_float4(0.f, 0.f, 0.f, 0.f);

  // ---- wave task: (b, r, c0) ----
  const int2 d = tab[blockIdx.x * 4 + wave];   // wave-uniform broadcast load
  const int r = d.x >> 16;
  const int c0 = d.x & 0xffff;
  const int b = d.y;
  const float cw = cwsgw[0], sgw = cwsgw[1];

  // A-row (shared by all 64 edges of this wave): lane's fixed k-slice, loaded once
  const float4* pa = (const float4*)(A + (b * NN + r) * FF);
  const float4 a0 = pa[2 * q], a1 = pa[2 * q + 1];
  const float4 a2 = pa[8 + 2 * q], a3 = pa[8 + 2 * q + 1];
  const float4* __restrict__ pb4 = (const float4*)Bv;   // [16][BN] float4
  const int colbase = b * NN + c0 + n;                  // + 16*et per pass

  __syncthreads();   // LDS tables visible; only barrier in the kernel

  // ---- prefetch pass 0 Bv ----
  float4 v0 = pb4[(2 * q) * BN + colbase];
  float4 v1 = pb4[(2 * q + 1) * BN + colbase];
  float4 v2 = pb4[(8 + 2 * q) * BN + colbase];
  float4 v3 = pb4[(8 + 2 * q + 1) * BN + colbase];

#pragma unroll
  for (int et = 0; et < 4; ++et) {
    // issue next pass's loads before this pass's compute
    float4 nv0, nv1, nv2, nv3;
    if (et < 3) {
      const int cnx = colbase + 16 * (et + 1);
      nv0 = pb4[(2 * q) * BN + cnx];
      nv1 = pb4[(2 * q + 1) * BN + cnx];
      nv2 = pb4[(8 + 2 * q) * BN + cnx];
      nv3 = pb4[(8 + 2 * q + 1) * BN + cnx];
    }

    const float x0 = fmaxf(a0.x + v0.x, 0.f);
    const float x1 = fmaxf(a0.y + v0.y, 0.f);
    const float x2 = fmaxf(a0.z + v0.z, 0.f);
    const float x3 = fmaxf(a0.w + v0.w, 0.f);
    const float x4 = fmaxf(a1.x + v1.x, 0.f);
    const float x5 = fmaxf(a1.y + v1.y, 0.f);
    const float x6 = fmaxf(a1.z + v1.z, 0.f);
    const float x7 = fmaxf(a1.w + v1.w, 0.f);
    const float x8 = fmaxf(a2.x + v2.x, 0.f);
    const float x9 = fmaxf(a2.y + v2.y, 0.f);
    const float x10 = fmaxf(a2.z + v2.z, 0.f);
    const float x11 = fmaxf(a2.w + v2.w, 0.f);
    const float x12 = fmaxf(a3.x + v3.x, 0.f);
    const float x13 = fmaxf(a3.y + v3.y, 0.f);
    const float x14 = fmaxf(a3.z + v3.z, 0.f);
    const float x15 = fmaxf(a3.w + v3.w, 0.f);

    // split into MFMA B-operand limbs (jj order = consecutive k)
    uint32_t h0, l0, h1, l1, h2, l2, h3, l3;
    split_pair(x0, x1, h0, l0); split_pair(x2, x3, h1, l1);
    split_pair(x4, x5, h2, l2); split_pair(x6, x7, h3, l3);
    const uint4v hv0 = {h0, h1, h2, h3}, lv0 = {l0, l1, l2, l3};
    const half8 xh0 = __builtin_bit_cast(half8, hv0);
    const half8 xl0 = __builtin_bit_cast(half8, lv0);
    split_pair(x8, x9, h0, l0);  split_pair(x10, x11, h1, l1);
    split_pair(x12, x13, h2, l2); split_pair(x14, x15, h3, l3);
    const uint4v hv1 = {h0, h1, h2, h3}, lv1 = {l0, l1, l2, l3};
    const half8 xh1 = __builtin_bit_cast(half8, hv1);
    const half8 xl1 = __builtin_bit_cast(half8, lv1);

    // LN1 stats: per-lane 16-elem partials, then cross-q tree (commutative adds
    // -> bit-identical in all 4 q-lanes of the edge)
    float s = x0 + x1 + x2 + x3 + x4 + x5 + x6 + x7 +
              x8 + x9 + x10 + x11 + x12 + x13 + x14 + x15;
    float qa = 0.f;
    qa = fmaf(x0, x0, qa); qa = fmaf(x1, x1, qa);
    qa = fmaf(x2, x2, qa); qa = fmaf(x3, x3, qa);
    qa = fmaf(x4, x4, qa); qa = fmaf(x5, x5, qa);
    qa = fmaf(x6, x6, qa); qa = fmaf(x7, x7, qa);
    qa = fmaf(x8, x8, qa); qa = fmaf(x9, x9, qa);
    qa = fmaf(x10, x10, qa); qa = fmaf(x11, x11, qa);
    qa = fmaf(x12, x12, qa); qa = fmaf(x13, x13, qa);
    qa = fmaf(x14, x14, qa); qa = fmaf(x15, x15, qa);
    s += __shfl_xor(s, 16, 64);  s += __shfl_xor(s, 32, 64);
    qa += __shfl_xor(qa, 16, 64); qa += __shfl_xor(qa, 32, 64);
    const float mu = s * (1.f / FF);
    const float rstd = 1.f / sqrtf(qa * (1.f / FF) - mu * mu + 1e-5f);

    // ---- MFMA: W frags streamed from LDS (conflict-free b128 reads) ----
    floatx4 acc0[4], acc1[4];
#pragma unroll
    for (int jt = 0; jt < 4; ++jt) {
      acc0[jt] = (floatx4){0.f, 0.f, 0.f, 0.f};
      acc1[jt] = (floatx4){0.f, 0.f, 0.f, 0.f};
    }
#pragma unroll
    for (int kc = 0; kc < 2; ++kc) {
      const half8 xh = kc ? xh1 : xh0;
      const half8 xl = kc ? xl1 : xl0;
#pragma unroll
      for (int jt = 0; jt < 4; ++jt) {
        const int woff = (((jt * 2 + kc) * 4 + q) * 16 + n) * 8;
        const half8 wh = *(const half8*)&WhS[woff];
        const half8 wl = *(const half8*)&WlS[woff];
        acc0[jt] = __builtin_amdgcn_mfma_f32_16x16x32_f16(wh, xh, acc0[jt], 0, 0, 0);
        acc1[jt] = __builtin_amdgcn_mfma_f32_16x16x32_f16(wh, xl, acc1[jt], 0, 0, 0);
        acc1[jt] = __builtin_amdgcn_mfma_f32_16x16x32_f16(wl, xh, acc1[jt], 0, 0, 0);
      }
    }

    // ---- epilogue: LN1-apply + relu + LN2-reduce (D col = n -> all lane-local) ----
    float s1 = 0.f, sq2 = 0.f, s3 = 0.f;
#pragma unroll
    for (int jt = 0; jt < 4; ++jt) {
      const floatx4 wc4 = *(const floatx4*)&wcolS[16 * jt + 4 * q];
      const floatx4 cb4 = *(const floatx4*)&cbS[16 * jt + 4 * q];
      const floatx4 gw4 = *(const floatx4*)&gwS[16 * jt + 4 * q];
      const floatx4 t4 = acc0[jt] + acc1[jt] * (1.f / 512.f);
#pragma unroll
      for (int rg = 0; rg < 4; ++rg) {
        const float pre = fmaf(rstd, fmaf(-mu, wc4[rg], t4[rg]), cb4[rg]);
        const float tr = fmaxf(pre, 0.f);
        s1 += tr;
        sq2 = fmaf(tr, tr, sq2);
        s3 = fmaf(tr, gw4[rg], s3);
      }
    }
    // sum over the 4 quads (disjoint 16-j subsets)
    s1 += __shfl_xor(s1, 16, 64);  s1 += __shfl_xor(s1, 32, 64);
    sq2 += __shfl_xor(sq2, 16, 64); sq2 += __shfl_xor(sq2, 32, 64);
    s3 += __shfl_xor(s3, 16, 64);  s3 += __shfl_xor(s3, 32, 64);
    const int c2 = c0 + 16 * et + n;
    if (q == 0 && c2 < r) {
      const float mu2 = s1 * (1.f / FF);
      const float var2 = sq2 * (1.f / FF) - mu2 * mu2;
      const float rstd2 = 1.f / sqrtf(var2 + 1e-5f);
      const float logit = fmaf(rstd2, fmaf(-mu2, sgw, s3), cw);
      L[(b * NSINK + (r - TT)) * NSRC + c2] = logit;
    }

    if (et < 3) { v0 = nv0; v1 = nv1; v2 = nv2; v3 = nv3; }
  }
}

// ---------------- argmax over sources + scatter ones ----------------
// One wave per (b, row) pair; all S=5 samples fused (L row read once).
__global__ __launch_bounds__(256) void argmax_scatter(
    const float* __restrict__ L, const float* __restrict__ gum,
    float* __restrict__ out) {
  const int pair = blockIdx.x * 4 + (threadIdx.x >> 6);  // b*192 + row
  const int lane = threadIdx.x & 63;
  const int row = pair % NSINK;
  const int b = pair / NSINK;
  const int r = row + TT;

  const float* __restrict__ lrow = L + (b * NSINK + row) * NSRC;
  const float* __restrict__ g0 = gum + (b * NSINK + row) * NSRC;
  const int sstr = BB * NSINK * NSRC;   // sample stride in floats

  float bv0 = -INFINITY, bv1 = -INFINITY, bv2 = -INFINITY, bv3 = -INFINITY, bv4 = -INFINITY;
  int bi0 = 0, bi1 = 0, bi2 = 0, bi3 = 0, bi4 = 0;
  for (int cc = lane; cc < r; cc += 64) {
    const float lv = lrow[cc];
    const float v0 = lv + g0[0 * sstr + cc];
    const float v1 = lv + g0[1 * sstr + cc];
    const float v2 = lv + g0[2 * sstr + cc];
    const float v3 = lv + g0[3 * sstr + cc];
    const float v4 = lv + g0[4 * sstr + cc];
    if (v0 > bv0) { bv0 = v0; bi0 = cc; }   // strict > keeps smallest index per lane
    if (v1 > bv1) { bv1 = v1; bi1 = cc; }
    if (v2 > bv2) { bv2 = v2; bi2 = cc; }
    if (v3 > bv3) { bv3 = v3; bi3 = cc; }
    if (v4 > bv4) { bv4 = v4; bi4 = cc; }
  }
#pragma unroll
  for (int off = 32; off > 0; off >>= 1) {
    {
      const float ov = __shfl_xor(bv0, off, 64); const int oi = __shfl_xor(bi0, off, 64);
      if (ov > bv0 || (ov == bv0 && oi < bi0)) { bv0 = ov; bi0 = oi; }
    }
    {
      const float ov = __shfl_xor(bv1, off, 64); const int oi = __shfl_xor(bi1, off, 64);
      if (ov > bv1 || (ov == bv1 && oi < bi1)) { bv1 = ov; bi1 = oi; }
    }
    {
      const float ov = __shfl_xor(bv2, off, 64); const int oi = __shfl_xor(bi2, off, 64);
      if (ov > bv2 || (ov == bv2 && oi < bi2)) { bv2 = ov; bi2 = oi; }
    }
    {
      const float ov = __shfl_xor(bv3, off, 64); const int oi = __shfl_xor(bi3, off, 64);
      if (ov > bv3 || (ov == bv3 && oi < bi3)) { bv3 = ov; bi3 = oi; }
    }
    {
      const float ov = __shfl_xor(bv4, off, 64); const int oi = __shfl_xor(bi4, off, 64);
      if (ov > bv4 || (ov == bv4 && oi < bi4)) { bv4 = ov; bi4 = oi; }
    }
  }
  if (lane == 0) {
    float* __restrict__ orow = out + (b * NN + r) * NN;
    orow[bi0] = 1.0f;
    orow[bi1] = 1.0f;
    orow[bi2] = 1.0f;
    orow[bi3] = 1.0f;
    orow[bi4] = 1.0f;
  }
}

extern "C" void kernel_launch(void* const* d_in, const int* in_sizes, int n_in,
                              void* d_out, int out_size, void* d_ws, size_t ws_size,
                              hipStream_t stream) {
  const float* nodes = (const float*)d_in[0];
  const float* w1 = (const float*)d_in[1];
  const float* b1 = (const float*)d_in[2];
  const float* g1 = (const float*)d_in[3];
  const float* be1 = (const float*)d_in[4];
  const float* w2 = (const float*)d_in[5];
  const float* b2 = (const float*)d_in[6];
  const float* g2 = (const float*)d_in[7];
  const float* be2 = (const float*)d_in[8];
  const float* w3 = (const float*)d_in[9];
  const float* b3 = (const float*)d_in[10];
  const float* gum = (const float*)d_in[11];
  float* out = (float*)d_out;

  // workspace layout (floats)
  float* ws = (float*)d_ws;
  float* A = ws;                       // 8*384*64 = 196608
  float* Bv = A + BN * FF;             // 196608 (f-major-blocked float4 layout)
  unsigned short* Whg = (unsigned short*)(ws + 393216);  // 4096 ushort (8 KB)
  unsigned short* Wlg = Whg + 4096;                      // 4096 ushort -> ends at float 397312
  float* wcol = ws + 397312;           // 64
  float* cb = wcol + FF;               // 64
  float* gw = cb + FF;                 // 64
  float* cwsgw = gw + FF;              // 2
  float* L = ws + 397520;              // 8*192*383 = 588288 -> ends at 985808
  int2* tab = (int2*)(ws + 985808);    // 7656 int2 (61 KB)
  (void)ws_size; (void)n_in; (void)in_sizes; (void)out_size;

  hipLaunchKernelGGL(prep_all, dim3(BN / 4 + 2), dim3(64), 0, stream,
                     nodes, w1, b1, w2, b2, g1, be1, g2, be2, w3, b3,
                     A, Bv, Whg, Wlg, wcol, cb, gw, cwsgw, tab);
  hipLaunchKernelGGL(edge_mlp, dim3(NBLK_T), dim3(256), 0, stream,
                     A, Bv, Whg, Wlg, wcol, cb, gw, cwsgw, tab, L,
                     (float4*)out);
  hipLaunchKernelGGL(argmax_scatter, dim3((BB * NSINK) / 4), dim3(256), 0, stream,
                     L, gum, out);
}

// Round 4
// 128.541 us; speedup vs baseline: 1.0276x; 1.0040x over previous
//
#include <hip/hip_runtime.h>
#include <math.h>
#include <stdint.h>

// Problem constants (static per reference)
#define BB 8
#define NN 384
#define FF 64
#define TT 192
#define NSRC 383          // T + TAU - 1
#define NSINK 192
#define SS 5
#define NEDGE 441600      // B * 55200
#define BN (BB * NN)      // 3072
#define OUTV ((BB * NN * NN) / 4) // 294912 float4 to zero
#define TPB_TASK 957      // wave-tiles per batch: 3 + 4*64 + 5*64 + 6*63
#define NTASK (BB * TPB_TASK)     // 7656
#define NBLK_T (NTASK / 4)        // 1914 blocks of 4 waves

typedef _Float16 half8 __attribute__((ext_vector_type(8)));
typedef __fp16 fp16x2 __attribute__((ext_vector_type(2)));
typedef float floatx4 __attribute__((ext_vector_type(4)));
typedef uint32_t uint4v __attribute__((ext_vector_type(4)));

// 2-limb f16 split (prep side, RNE): x ~= h + l/512
static __device__ __forceinline__ void split_f16(float x, uint16_t& h, uint16_t& l) {
  const _Float16 hh = (_Float16)x;
  const float hb = (float)hh;
  const _Float16 ll = (_Float16)((x - hb) * 512.f);
  h = __builtin_bit_cast(uint16_t, hh);
  l = __builtin_bit_cast(uint16_t, ll);
}

// pair split via v_cvt_pkrtz (RTZ hi; residual captured exactly by the lo limb)
static __device__ __forceinline__ void split_pair(float x0, float x1,
                                                  uint32_t& hi, uint32_t& lo) {
  const fp16x2 h = __builtin_amdgcn_cvt_pkrtz(x0, x1);
  const float hb0 = (float)h.x, hb1 = (float)h.y;
  const fp16x2 l = __builtin_amdgcn_cvt_pkrtz((x0 - hb0) * 512.f, (x1 - hb1) * 512.f);
  hi = __builtin_bit_cast(uint32_t, h);
  lo = __builtin_bit_cast(uint32_t, l);
}

// ---------------- prep: node projections + weight folding + W frags + task table ----------------
// A stays row-major [bn][f].
// Bv is stored f-major-blocked: float4 element index = (f>>2)*BN + bn, component f&3.
// W frag slab (A-operand layout, per limb): ushort idx = (((jt*2+kc)*4+q)*16 + m)*8 + jj
//   <-> W[k = 32*kc + 8*q + jj][j = 16*jt + m]   (g1-folded weight)
// Task table: one entry per wave-tile {(r<<16)|c0, b}; row r has ceil(r/64) tiles.
__global__ __launch_bounds__(64) void prep_all(
    const float* __restrict__ nodes, const float* __restrict__ w1,
    const float* __restrict__ b1,
    const float* __restrict__ w2, const float* __restrict__ b2,
    const float* __restrict__ g1, const float* __restrict__ be1,
    const float* __restrict__ g2, const float* __restrict__ be2,
    const float* __restrict__ w3, const float* __restrict__ b3,
    float* __restrict__ A, float* __restrict__ Bv,
    unsigned short* __restrict__ Whg, unsigned short* __restrict__ Wlg,
    float* __restrict__ wcol, float* __restrict__ cb,
    float* __restrict__ gw, float* __restrict__ cwsgw,
    int2* __restrict__ tab) {
  const int blk = blockIdx.x;
  const int k = threadIdx.x;
  if (blk < BN / 4) {
    const int bn0 = blk * 4;
    __shared__ float nd[4][FF];
#pragma unroll
    for (int i = 0; i < 4; ++i) nd[i][k] = nodes[(bn0 + i) * FF + k];
    __syncthreads();
    const float bk = b1[k];
    float a0 = bk, a1 = bk, a2 = bk, a3 = bk;
    float q0 = 0.f, q1 = 0.f, q2 = 0.f, q3 = 0.f;
#pragma unroll 8
    for (int f = 0; f < FF; ++f) {
      const float wt = w1[f * FF + k];
      const float wb = w1[(FF + f) * FF + k];
      const float n0 = nd[0][f], n1 = nd[1][f], n2 = nd[2][f], n3 = nd[3][f];
      a0 = fmaf(n0, wt, a0); a1 = fmaf(n1, wt, a1);
      a2 = fmaf(n2, wt, a2); a3 = fmaf(n3, wt, a3);
      q0 = fmaf(n0, wb, q0); q1 = fmaf(n1, wb, q1);
      q2 = fmaf(n2, wb, q2); q3 = fmaf(n3, wb, q3);
    }
    A[(bn0 + 0) * FF + k] = a0;
    A[(bn0 + 1) * FF + k] = a1;
    A[(bn0 + 2) * FF + k] = a2;
    A[(bn0 + 3) * FF + k] = a3;
    // transposed (f-major-blocked) Bv writes
    const int f4 = k >> 2, ff = k & 3;
    Bv[(f4 * BN + (bn0 + 0)) * 4 + ff] = q0;
    Bv[(f4 * BN + (bn0 + 1)) * 4 + ff] = q1;
    Bv[(f4 * BN + (bn0 + 2)) * 4 + ff] = q2;
    Bv[(f4 * BN + (bn0 + 3)) * 4 + ff] = q3;
  } else if (blk == BN / 4) {
    const int j = k;
    const int jt = j >> 4, m = j & 15;
    float cbj = b2[j];
    float wc = 0.f;
    for (int kk = 0; kk < FF; ++kk) {
      const float wraw = w2[kk * FF + j];
      const float w = g1[kk] * wraw;
      wc += w;
      cbj = fmaf(be1[kk], wraw, cbj);
      uint16_t hu, lu;
      split_f16(w, hu, lu);
      const int kc = kk >> 5, qq = (kk >> 3) & 3, jj = kk & 7;
      const int idx = (((jt * 2 + kc) * 4 + qq) * 16 + m) * 8 + jj;
      Whg[idx] = hu;
      Wlg[idx] = lu;
    }
    wcol[j] = wc;
    cb[j] = cbj;
    const float gwj = g2[j] * w3[j];
    gw[j] = gwj;
    __shared__ float sA[FF], sB[FF];
    sA[j] = gwj;
    sB[j] = be2[j] * w3[j];
    __syncthreads();
    if (j == 0) {
      float a = 0.f, bq = 0.f;
      for (int i = 0; i < FF; ++i) { a += sA[i]; bq += sB[i]; }
      cwsgw[0] = b3[0] + bq;
      cwsgw[1] = a;
    }
  } else {
    // ---- wave-task table: cumulative-tile closed form ----
    for (int rr = k; rr < NSINK; rr += 64) {
      const int r = TT + rr;
      int tb;
      if (r == 192) tb = 0;
      else if (r < 257) tb = 3 + 4 * (r - 193);
      else if (r < 321) tb = 259 + 5 * (r - 257);
      else tb = 579 + 6 * (r - 321);
      const int nt = (r + 63) >> 6;
      for (int b = 0; b < BB; ++b)
        for (int i = 0; i < nt; ++i)
          tab[b * TPB_TASK + tb + i] = make_int2((r << 16) | (i * 64), b);
    }
  }
}

// ---------------- main: MFMA edge MLP, row-tiled, transpose-free ----------------
// 256 thr = 4 waves; wave owns one task (b, r, c0): 64 consecutive source cols of
// one sink row, 4 passes of 16 edges. Lane role (q=lane>>4, n=lane&15) IS the MFMA
// B-frag layout. A-row loaded once per wave. No software prefetch: occupancy is the
// latency-hiding mechanism (4 blocks/CU, 16 waves/CU). LDS: 16 KB W table + consts.
__global__ __launch_bounds__(256, 4) void edge_mlp(
    const float* __restrict__ A, const float* __restrict__ Bv,
    const unsigned short* __restrict__ Whg, const unsigned short* __restrict__ Wlg,
    const float* __restrict__ wcolg, const float* __restrict__ cbg,
    const float* __restrict__ gwg, const float* __restrict__ cwsgw,
    const int2* __restrict__ tab, float* __restrict__ L,
    float4* __restrict__ outv) {
  __shared__ __align__(16) unsigned short WhS[4096];   // 8 KB W hi frags
  __shared__ __align__(16) unsigned short WlS[4096];   // 8 KB W lo frags
  __shared__ __align__(16) float wcolS[FF], cbS[FF], gwS[FF];

  const int tid = threadIdx.x;       // 0..255
  const int wave = tid >> 6;
  const int lane = tid & 63;
  const int q = lane >> 4;           // k-quad
  const int n = lane & 15;           // edge column within pass

  // ---- wave task first: get global loads in flight early ----
  const int2 d = tab[blockIdx.x * 4 + wave];   // wave-uniform broadcast load
  const int r = d.x >> 16;
  const int c0 = d.x & 0xffff;
  const int b = d.y;

  // A-row (shared by all 64 edges of this wave): lane's fixed k-slice, loaded once
  const float4* pa = (const float4*)(A + (b * NN + r) * FF);
  const float4 a0 = pa[2 * q], a1 = pa[2 * q + 1];
  const float4 a2 = pa[8 + 2 * q], a3 = pa[8 + 2 * q + 1];
  const float4* __restrict__ pb4 = (const float4*)Bv;   // [16][BN] float4
  const int colbase = b * NN + c0 + n;                  // + 16*et per pass

  // ---- stage W frag table + epilogue constants into LDS ----
  {
    const int4* gh = (const int4*)Whg;
    const int4* gl = (const int4*)Wlg;
    int4* sh = (int4*)WhS;
    int4* sl = (int4*)WlS;
    sh[tid] = gh[tid];
    sh[tid + 256] = gh[tid + 256];
    sl[tid] = gl[tid];
    sl[tid + 256] = gl[tid + 256];
    if (tid < FF) {
      wcolS[tid] = wcolg[tid];
      cbS[tid] = cbg[tid];
      gwS[tid] = gwg[tid];
    }
  }

  // fused zeroing of the output grid
  const int gtid = blockIdx.x * 256 + tid;
  if (gtid < OUTV) outv[gtid] = make_float4(0.f, 0.f, 0.f, 0.f);

  const float cw = cwsgw[0], sgw = cwsgw[1];

  __syncthreads();   // LDS tables visible; only barrier in the kernel

#pragma unroll
  for (int et = 0; et < 4; ++et) {
    const int col = colbase + 16 * et;
    const float4 v0 = pb4[(2 * q) * BN + col];
    const float4 v1 = pb4[(2 * q + 1) * BN + col];
    const float4 v2 = pb4[(8 + 2 * q) * BN + col];
    const float4 v3 = pb4[(8 + 2 * q + 1) * BN + col];

    const float x0 = fmaxf(a0.x + v0.x, 0.f);
    const float x1 = fmaxf(a0.y + v0.y, 0.f);
    const float x2 = fmaxf(a0.z + v0.z, 0.f);
    const float x3 = fmaxf(a0.w + v0.w, 0.f);
    const float x4 = fmaxf(a1.x + v1.x, 0.f);
    const float x5 = fmaxf(a1.y + v1.y, 0.f);
    const float x6 = fmaxf(a1.z + v1.z, 0.f);
    const float x7 = fmaxf(a1.w + v1.w, 0.f);
    const float x8 = fmaxf(a2.x + v2.x, 0.f);
    const float x9 = fmaxf(a2.y + v2.y, 0.f);
    const float x10 = fmaxf(a2.z + v2.z, 0.f);
    const float x11 = fmaxf(a2.w + v2.w, 0.f);
    const float x12 = fmaxf(a3.x + v3.x, 0.f);
    const float x13 = fmaxf(a3.y + v3.y, 0.f);
    const float x14 = fmaxf(a3.z + v3.z, 0.f);
    const float x15 = fmaxf(a3.w + v3.w, 0.f);

    // split into MFMA B-operand limbs (jj order = consecutive k)
    uint32_t h0, l0, h1, l1, h2, l2, h3, l3;
    split_pair(x0, x1, h0, l0); split_pair(x2, x3, h1, l1);
    split_pair(x4, x5, h2, l2); split_pair(x6, x7, h3, l3);
    const uint4v hv0 = {h0, h1, h2, h3}, lv0 = {l0, l1, l2, l3};
    const half8 xh0 = __builtin_bit_cast(half8, hv0);
    const half8 xl0 = __builtin_bit_cast(half8, lv0);
    split_pair(x8, x9, h0, l0);  split_pair(x10, x11, h1, l1);
    split_pair(x12, x13, h2, l2); split_pair(x14, x15, h3, l3);
    const uint4v hv1 = {h0, h1, h2, h3}, lv1 = {l0, l1, l2, l3};
    const half8 xh1 = __builtin_bit_cast(half8, hv1);
    const half8 xl1 = __builtin_bit_cast(half8, lv1);

    // LN1 stats: per-lane 16-elem partials, then cross-q tree (commutative adds
    // -> bit-identical in all 4 q-lanes of the edge)
    float s = x0 + x1 + x2 + x3 + x4 + x5 + x6 + x7 +
              x8 + x9 + x10 + x11 + x12 + x13 + x14 + x15;
    float qa = 0.f;
    qa = fmaf(x0, x0, qa); qa = fmaf(x1, x1, qa);
    qa = fmaf(x2, x2, qa); qa = fmaf(x3, x3, qa);
    qa = fmaf(x4, x4, qa); qa = fmaf(x5, x5, qa);
    qa = fmaf(x6, x6, qa); qa = fmaf(x7, x7, qa);
    qa = fmaf(x8, x8, qa); qa = fmaf(x9, x9, qa);
    qa = fmaf(x10, x10, qa); qa = fmaf(x11, x11, qa);
    qa = fmaf(x12, x12, qa); qa = fmaf(x13, x13, qa);
    qa = fmaf(x14, x14, qa); qa = fmaf(x15, x15, qa);
    s += __shfl_xor(s, 16, 64);  s += __shfl_xor(s, 32, 64);
    qa += __shfl_xor(qa, 16, 64); qa += __shfl_xor(qa, 32, 64);
    const float mu = s * (1.f / FF);
    const float rstd = 1.f / sqrtf(qa * (1.f / FF) - mu * mu + 1e-5f);

    // ---- MFMA: W frags streamed from LDS (conflict-free b128 reads) ----
    floatx4 acc0[4], acc1[4];
#pragma unroll
    for (int jt = 0; jt < 4; ++jt) {
      acc0[jt] = (floatx4){0.f, 0.f, 0.f, 0.f};
      acc1[jt] = (floatx4){0.f, 0.f, 0.f, 0.f};
    }
    __builtin_amdgcn_s_setprio(1);
#pragma unroll
    for (int kc = 0; kc < 2; ++kc) {
      const half8 xh = kc ? xh1 : xh0;
      const half8 xl = kc ? xl1 : xl0;
#pragma unroll
      for (int jt = 0; jt < 4; ++jt) {
        const int woff = (((jt * 2 + kc) * 4 + q) * 16 + n) * 8;
        const half8 wh = *(const half8*)&WhS[woff];
        const half8 wl = *(const half8*)&WlS[woff];
        acc0[jt] = __builtin_amdgcn_mfma_f32_16x16x32_f16(wh, xh, acc0[jt], 0, 0, 0);
        acc1[jt] = __builtin_amdgcn_mfma_f32_16x16x32_f16(wh, xl, acc1[jt], 0, 0, 0);
        acc1[jt] = __builtin_amdgcn_mfma_f32_16x16x32_f16(wl, xh, acc1[jt], 0, 0, 0);
      }
    }
    __builtin_amdgcn_s_setprio(0);

    // ---- epilogue: LN1-apply + relu + LN2-reduce (D col = n -> all lane-local) ----
    float s1 = 0.f, sq2 = 0.f, s3 = 0.f;
#pragma unroll
    for (int jt = 0; jt < 4; ++jt) {
      const floatx4 wc4 = *(const floatx4*)&wcolS[16 * jt + 4 * q];
      const floatx4 cb4 = *(const floatx4*)&cbS[16 * jt + 4 * q];
      const floatx4 gw4 = *(const floatx4*)&gwS[16 * jt + 4 * q];
      const floatx4 t4 = acc0[jt] + acc1[jt] * (1.f / 512.f);
#pragma unroll
      for (int rg = 0; rg < 4; ++rg) {
        const float pre = fmaf(rstd, fmaf(-mu, wc4[rg], t4[rg]), cb4[rg]);
        const float tr = fmaxf(pre, 0.f);
        s1 += tr;
        sq2 = fmaf(tr, tr, sq2);
        s3 = fmaf(tr, gw4[rg], s3);
      }
    }
    // sum over the 4 quads (disjoint 16-j subsets)
    s1 += __shfl_xor(s1, 16, 64);  s1 += __shfl_xor(s1, 32, 64);
    sq2 += __shfl_xor(sq2, 16, 64); sq2 += __shfl_xor(sq2, 32, 64);
    s3 += __shfl_xor(s3, 16, 64);  s3 += __shfl_xor(s3, 32, 64);
    const int c2 = c0 + 16 * et + n;
    if (q == 0 && c2 < r) {
      const float mu2 = s1 * (1.f / FF);
      const float var2 = sq2 * (1.f / FF) - mu2 * mu2;
      const float rstd2 = 1.f / sqrtf(var2 + 1e-5f);
      const float logit = fmaf(rstd2, fmaf(-mu2, sgw, s3), cw);
      L[(b * NSINK + (r - TT)) * NSRC + c2] = logit;
    }
  }
}

// ---------------- argmax over sources + scatter ones ----------------
// One wave per (b, row) pair; all S=5 samples fused (L row read once).
__global__ __launch_bounds__(256) void argmax_scatter(
    const float* __restrict__ L, const float* __restrict__ gum,
    float* __restrict__ out) {
  const int pair = blockIdx.x * 4 + (threadIdx.x >> 6);  // b*192 + row
  const int lane = threadIdx.x & 63;
  const int row = pair % NSINK;
  const int b = pair / NSINK;
  const int r = row + TT;

  const float* __restrict__ lrow = L + (b * NSINK + row) * NSRC;
  const float* __restrict__ g0 = gum + (b * NSINK + row) * NSRC;
  const int sstr = BB * NSINK * NSRC;   // sample stride in floats

  float bv0 = -INFINITY, bv1 = -INFINITY, bv2 = -INFINITY, bv3 = -INFINITY, bv4 = -INFINITY;
  int bi0 = 0, bi1 = 0, bi2 = 0, bi3 = 0, bi4 = 0;
  for (int cc = lane; cc < r; cc += 64) {
    const float lv = lrow[cc];
    const float v0 = lv + g0[0 * sstr + cc];
    const float v1 = lv + g0[1 * sstr + cc];
    const float v2 = lv + g0[2 * sstr + cc];
    const float v3 = lv + g0[3 * sstr + cc];
    const float v4 = lv + g0[4 * sstr + cc];
    if (v0 > bv0) { bv0 = v0; bi0 = cc; }   // strict > keeps smallest index per lane
    if (v1 > bv1) { bv1 = v1; bi1 = cc; }
    if (v2 > bv2) { bv2 = v2; bi2 = cc; }
    if (v3 > bv3) { bv3 = v3; bi3 = cc; }
    if (v4 > bv4) { bv4 = v4; bi4 = cc; }
  }
#pragma unroll
  for (int off = 32; off > 0; off >>= 1) {
    {
      const float ov = __shfl_xor(bv0, off, 64); const int oi = __shfl_xor(bi0, off, 64);
      if (ov > bv0 || (ov == bv0 && oi < bi0)) { bv0 = ov; bi0 = oi; }
    }
    {
      const float ov = __shfl_xor(bv1, off, 64); const int oi = __shfl_xor(bi1, off, 64);
      if (ov > bv1 || (ov == bv1 && oi < bi1)) { bv1 = ov; bi1 = oi; }
    }
    {
      const float ov = __shfl_xor(bv2, off, 64); const int oi = __shfl_xor(bi2, off, 64);
      if (ov > bv2 || (ov == bv2 && oi < bi2)) { bv2 = ov; bi2 = oi; }
    }
    {
      const float ov = __shfl_xor(bv3, off, 64); const int oi = __shfl_xor(bi3, off, 64);
      if (ov > bv3 || (ov == bv3 && oi < bi3)) { bv3 = ov; bi3 = oi; }
    }
    {
      const float ov = __shfl_xor(bv4, off, 64); const int oi = __shfl_xor(bi4, off, 64);
      if (ov > bv4 || (ov == bv4 && oi < bi4)) { bv4 = ov; bi4 = oi; }
    }
  }
  if (lane == 0) {
    float* __restrict__ orow = out + (b * NN + r) * NN;
    orow[bi0] = 1.0f;
    orow[bi1] = 1.0f;
    orow[bi2] = 1.0f;
    orow[bi3] = 1.0f;
    orow[bi4] = 1.0f;
  }
}

extern "C" void kernel_launch(void* const* d_in, const int* in_sizes, int n_in,
                              void* d_out, int out_size, void* d_ws, size_t ws_size,
                              hipStream_t stream) {
  const float* nodes = (const float*)d_in[0];
  const float* w1 = (const float*)d_in[1];
  const float* b1 = (const float*)d_in[2];
  const float* g1 = (const float*)d_in[3];
  const float* be1 = (const float*)d_in[4];
  const float* w2 = (const float*)d_in[5];
  const float* b2 = (const float*)d_in[6];
  const float* g2 = (const float*)d_in[7];
  const float* be2 = (const float*)d_in[8];
  const float* w3 = (const float*)d_in[9];
  const float* b3 = (const float*)d_in[10];
  const float* gum = (const float*)d_in[11];
  float* out = (float*)d_out;

  // workspace layout (floats)
  float* ws = (float*)d_ws;
  float* A = ws;                       // 8*384*64 = 196608
  float* Bv = A + BN * FF;             // 196608 (f-major-blocked float4 layout)
  unsigned short* Whg = (unsigned short*)(ws + 393216);  // 4096 ushort (8 KB)
  unsigned short* Wlg = Whg + 4096;                      // 4096 ushort -> ends at float 397312
  float* wcol = ws + 397312;           // 64
  float* cb = wcol + FF;               // 64
  float* gw = cb + FF;                 // 64
  float* cwsgw = gw + FF;              // 2
  float* L = ws + 397520;              // 8*192*383 = 588288 -> ends at 985808
  int2* tab = (int2*)(ws + 985808);    // 7656 int2 (61 KB)
  (void)ws_size; (void)n_in; (void)in_sizes; (void)out_size;

  hipLaunchKernelGGL(prep_all, dim3(BN / 4 + 2), dim3(64), 0, stream,
                     nodes, w1, b1, w2, b2, g1, be1, g2, be2, w3, b3,
                     A, Bv, Whg, Wlg, wcol, cb, gw, cwsgw, tab);
  hipLaunchKernelGGL(edge_mlp, dim3(NBLK_T), dim3(256), 0, stream,
                     A, Bv, Whg, Wlg, wcol, cb, gw, cwsgw, tab, L,
                     (float4*)out);
  hipLaunchKernelGGL(argmax_scatter, dim3((BB * NSINK) / 4), dim3(256), 0, stream,
                     L, gum, out);
}